// Round 3
// baseline (545.030 us; speedup 1.0000x reference)
//
#include <hip/hip_runtime.h>
#include <cstdint>
#include <cstddef>

typedef unsigned short u16;
typedef __attribute__((ext_vector_type(8))) short short8;
typedef __attribute__((ext_vector_type(4))) float f32x4;

#define MFMA_B16(a,b,c) __builtin_amdgcn_mfma_f32_16x16x32_bf16((a),(b),(c),0,0,0)

#define S_LEN 2048
#define EMB 2048
#define QKV_N 6144
#define HD 64
#define LAMBDA_INIT_F 0.78360576653162f
#define ONE_MINUS_LI 0.21639423346838f

static __device__ __forceinline__ u16 f2bf(float f) {
  unsigned u = __float_as_uint(f);
  unsigned r = ((u >> 16) & 1u) + 0x7fffu;
  return (u16)((u + r) >> 16);
}
static __device__ __forceinline__ float bf2f(u16 h) {
  return __uint_as_float(((unsigned)h) << 16);
}
static __device__ __forceinline__ void gload_lds16(const u16* g, u16* l) {
  __builtin_amdgcn_global_load_lds((const __attribute__((address_space(1))) void*)g,
                                   (__attribute__((address_space(3))) void*)l, 16, 0, 0);
}

// ---------------- f32 -> bf16 convert (vectorized) ----------------
__global__ void cvt_f32_bf16(const float* __restrict__ s, u16* __restrict__ d, int n4) {
  int i = blockIdx.x * 256 + threadIdx.x;
  if (i >= n4) return;
  f32x4 v = *(const f32x4*)&s[i * 4];
  unsigned long long pk = (unsigned long long)f2bf(v[0])
                        | ((unsigned long long)f2bf(v[1]) << 16)
                        | ((unsigned long long)f2bf(v[2]) << 32)
                        | ((unsigned long long)f2bf(v[3]) << 48);
  *(unsigned long long*)&d[i * 4] = pk;
}

// ---------------- GEMM: C[M,N] = A[M,K] * B[N,K]^T  (bf16 in, f32 acc) ----------------
template <int BF16OUT>
__global__ __launch_bounds__(256, 2) void gemm_bt(const u16* __restrict__ A,
                                                  const u16* __restrict__ B,
                                                  void* __restrict__ Cout,
                                                  int M, int N, int K) {
  __shared__ u16 As[128 * 32];
  __shared__ u16 Bs[128 * 32];
  const int tid = threadIdx.x;
  const int lane = tid & 63, wv = tid >> 6;
  const int bm = blockIdx.x * 128, bn = blockIdx.y * 128;
  const int wr = (wv >> 1) * 64, wc = (wv & 1) * 64;
  const int lr = lane & 15, hk = lane >> 4;

  const int r0 = tid >> 2;
  const int c0 = (tid & 3) * 8;
  const u16* ga = A + (size_t)(bm + r0) * K + c0;
  const u16* gb = B + (size_t)(bn + r0) * K + c0;
  const size_t rstep = (size_t)64 * K;

  f32x4 acc[4][4] = {};

  for (int k0 = 0; k0 < K; k0 += 32) {
    __syncthreads();
    gload_lds16(ga + k0,         &As[(tid) * 8]);
    gload_lds16(ga + rstep + k0, &As[(tid + 256) * 8]);
    gload_lds16(gb + k0,         &Bs[(tid) * 8]);
    gload_lds16(gb + rstep + k0, &Bs[(tid + 256) * 8]);
    __syncthreads();
    short8 af[4], bfv[4];
#pragma unroll
    for (int i = 0; i < 4; i++) af[i] = *(const short8*)&As[(wr + i * 16 + lr) * 32 + hk * 8];
#pragma unroll
    for (int j = 0; j < 4; j++) bfv[j] = *(const short8*)&Bs[(wc + j * 16 + lr) * 32 + hk * 8];
#pragma unroll
    for (int i = 0; i < 4; i++)
#pragma unroll
      for (int j = 0; j < 4; j++)
        acc[i][j] = MFMA_B16(af[i], bfv[j], acc[i][j]);
  }

  if (BF16OUT) {
    u16* C = (u16*)Cout;
#pragma unroll
    for (int i = 0; i < 4; i++)
#pragma unroll
      for (int j = 0; j < 4; j++)
#pragma unroll
        for (int r = 0; r < 4; r++) {
          int row = bm + wr + i * 16 + hk * 4 + r;
          int col = bn + wc + j * 16 + lr;
          C[(size_t)row * N + col] = f2bf(acc[i][j][r]);
        }
  } else {
    float* C = (float*)Cout;
#pragma unroll
    for (int i = 0; i < 4; i++)
#pragma unroll
      for (int j = 0; j < 4; j++)
#pragma unroll
        for (int r = 0; r < 4; r++) {
          int row = bm + wr + i * 16 + hk * 4 + r;
          int col = bn + wc + j * 16 + lr;
          C[(size_t)row * N + col] = acc[i][j][r];
        }
  }
}

// ---------------- RoPE (interleaved, in place on q,k halves of qkv) ----------------
__global__ void rope_kernel(u16* __restrict__ qkv) {
  int idx = blockIdx.x * 256 + threadIdx.x;
  int p = idx & 31;
  int u = (idx >> 5) & 63;
  int m = idx >> 11;
  int t = m & (S_LEN - 1);
  int col = (u < 32) ? (u * 64 + 2 * p) : (EMB + (u - 32) * 64 + 2 * p);
  u16* ptr = qkv + (size_t)m * QKV_N + col;
  unsigned v = *(unsigned*)ptr;
  float xe = bf2f((u16)(v & 0xffff));
  float xo = bf2f((u16)(v >> 16));
  float w = expf((float)p * (-9.210340371976184f / 31.0f));
  float ang = (float)t * w;
  float sn, cs;
  sincosf(ang, &sn, &cs);
  float oe = xe * cs - xo * sn;
  float oo = xe * sn + xo * cs;
  *(unsigned*)ptr = (unsigned)f2bf(oe) | (((unsigned)f2bf(oo)) << 16);
}

// ---------------- fused dual-stream attention + lambda-combine + RMSNorm ----------------
// LDS: stride-64 rows (128 B) with XOR swizzle byte = row*128 + (colByte ^ ((row&7)<<4)).
#define SW(row, colByte) ((((row)) << 7) + ((colByte) ^ (((row) & 7) << 4)))

__global__ __launch_bounds__(256, 3) void attn_kernel(
    const u16* __restrict__ qkv, u16* __restrict__ attnb,
    const float* __restrict__ lq1, const float* __restrict__ lk1,
    const float* __restrict__ lq2, const float* __restrict__ lk2,
    const float* __restrict__ gamma) {
  __shared__ u16 K1s[64 * 64];
  __shared__ u16 K2s[64 * 64];
  __shared__ u16 VTs[128 * 64];
  __shared__ u16 Ps[4 * 2 * 16 * 64];  // per-wave P1,P2 sub-buffers of 16x64

  // XCD-clustered mapping: each XCD owns 4 (b,h) pairs -> K/V stays L2-resident
  const int g = blockIdx.x;
  const int xcd = g & 7;
  const int gi = g >> 3;
  const int bh = xcd * 4 + (gi >> 5);
  const int qt = gi & 31;
  const int b = bh >> 4, h = bh & 15;

  const int tid = threadIdx.x, lane = tid & 63, wv = tid >> 6;
  const int lr = lane & 15, hk = lane >> 4;

  // lambda via wave-parallel reduction (HD == 64 == wave width)
  float d1 = lq1[lane] * lk1[lane];
  float d2 = lq2[lane] * lk2[lane];
#pragma unroll
  for (int off = 32; off; off >>= 1) { d1 += __shfl_xor(d1, off); d2 += __shfl_xor(d2, off); }
  const float lam = __expf(d1) - __expf(d2) + LAMBDA_INIT_F;

  // Q fragments (B-operand of swapped QK^T)
  const int qrow = qt * 64 + wv * 16 + lr;
  const u16* qp = qkv + (size_t)(b * S_LEN + qrow) * QKV_N;
  short8 q1f[2], q2f[2];
  q1f[0] = *(const short8*)&qp[(2 * h) * 64 + hk * 8];
  q1f[1] = *(const short8*)&qp[(2 * h) * 64 + 32 + hk * 8];
  q2f[0] = *(const short8*)&qp[(2 * h + 1) * 64 + hk * 8];
  q2f[1] = *(const short8*)&qp[(2 * h + 1) * 64 + 32 + hk * 8];

  f32x4 o1a[8] = {};
  f32x4 o2a[8] = {};
  float l1p = 0.f, l2p = 0.f;

  const int sr = tid >> 3;            // K stage row (0..31), +32 for second half
  const int scc = (tid & 7) * 8;      // K stage col (elements)
  const int vkv = (tid & 31) * 2;     // V stage kv pair
  const int vd0 = (tid >> 5) * 8;     // V stage d block

  const u16* kb1 = qkv + (size_t)b * S_LEN * QKV_N + EMB + (2 * h) * 64;
  const u16* kb2 = kb1 + 64;
  const u16* vbp = qkv + (size_t)b * S_LEN * QKV_N + 2 * EMB + h * 128;

  char* P1 = (char*)&Ps[(wv * 2 + 0) * 16 * 64];
  char* P2 = (char*)&Ps[(wv * 2 + 1) * 16 * 64];
  char* K1c = (char*)K1s;
  char* K2c = (char*)K2s;
  char* VTc = (char*)VTs;

  // T14 staging in NAMED registers (no arrays -> no scratch; rule #20)
  short8 rk1a, rk1b, rk2a, rk2b, rv0a, rv0b, rv1a, rv1b;

#define LOADT(kv0_)                                                      \
  do {                                                                   \
    const u16* s1_ = kb1 + (size_t)((kv0_) + sr) * QKV_N + scc;          \
    const u16* s2_ = kb2 + (size_t)((kv0_) + sr) * QKV_N + scc;          \
    const u16* vs_ = vbp + (size_t)((kv0_) + vkv) * QKV_N + vd0;         \
    rk1a = *(const short8*)s1_;                                          \
    rk1b = *(const short8*)(s1_ + (size_t)32 * QKV_N);                   \
    rk2a = *(const short8*)s2_;                                          \
    rk2b = *(const short8*)(s2_ + (size_t)32 * QKV_N);                   \
    rv0a = *(const short8*)vs_;                                          \
    rv0b = *(const short8*)(vs_ + 64);                                   \
    rv1a = *(const short8*)(vs_ + QKV_N);                                \
    rv1b = *(const short8*)(vs_ + QKV_N + 64);                           \
  } while (0)

  LOADT(0);

  for (int kv0 = 0; kv0 < S_LEN; kv0 += 64) {
    __syncthreads();  // all waves done reading previous tile's LDS
    // write staged regs -> LDS (swizzled)
    *(short8*)(K1c + SW(sr,      scc * 2)) = rk1a;
    *(short8*)(K1c + SW(sr + 32, scc * 2)) = rk1b;
    *(short8*)(K2c + SW(sr,      scc * 2)) = rk2a;
    *(short8*)(K2c + SW(sr + 32, scc * 2)) = rk2b;
#pragma unroll
    for (int j = 0; j < 8; j++) {
      unsigned pk0 = (unsigned)(u16)rv0a[j] | (((unsigned)(u16)rv1a[j]) << 16);
      *(unsigned*)(VTc + SW(vd0 + j, vkv * 2)) = pk0;
      unsigned pk1 = (unsigned)(u16)rv0b[j] | (((unsigned)(u16)rv1b[j]) << 16);
      *(unsigned*)(VTc + SW(vd0 + 64 + j, vkv * 2)) = pk1;
    }
    // issue next tile's global loads now; latency hides under compute below
    if (kv0 + 64 < S_LEN) LOADT(kv0 + 64);
    __syncthreads();  // LDS tile ready

    // scores (swapped: S^T tile = mfma(K, Q)), exp, write P (bf16) to per-wave LDS
#pragma unroll
    for (int st = 0; st < 2; st++) {
      const char* Ks = st ? K2c : K1c;
      const short8* qf = st ? q2f : q1f;
      char* Pw = st ? P2 : P1;
      float lacc = 0.f;
#pragma unroll
      for (int kt = 0; kt < 4; kt++) {
        f32x4 s = {0.f, 0.f, 0.f, 0.f};
        int row = kt * 16 + lr;
        short8 ka0 = *(const short8*)(Ks + SW(row, hk * 16));
        short8 ka1 = *(const short8*)(Ks + SW(row, 64 + hk * 16));
        s = MFMA_B16(ka0, qf[0], s);
        s = MFMA_B16(ka1, qf[1], s);
        float e0 = __expf(s[0] * 0.125f);
        float e1 = __expf(s[1] * 0.125f);
        float e2 = __expf(s[2] * 0.125f);
        float e3 = __expf(s[3] * 0.125f);
        lacc += (e0 + e1) + (e2 + e3);
        unsigned long long pk = (unsigned long long)f2bf(e0)
                              | ((unsigned long long)f2bf(e1) << 16)
                              | ((unsigned long long)f2bf(e2) << 32)
                              | ((unsigned long long)f2bf(e3) << 48);
        *(unsigned long long*)(Pw + SW(lr, kt * 32 + hk * 8)) = pk;
      }
      if (st) l2p += lacc; else l1p += lacc;
    }
    asm volatile("" ::: "memory");  // keep P LDS writes ordered before P reads

    // PV: o^T = mfma(V^T, P^T); V fragments shared by both streams
    short8 p10 = *(const short8*)(P1 + SW(lr, hk * 16));
    short8 p11 = *(const short8*)(P1 + SW(lr, 64 + hk * 16));
    short8 p20 = *(const short8*)(P2 + SW(lr, hk * 16));
    short8 p21 = *(const short8*)(P2 + SW(lr, 64 + hk * 16));
#pragma unroll
    for (int dt = 0; dt < 8; dt++) {
      int row = dt * 16 + lr;
      short8 va0 = *(const short8*)(VTc + SW(row, hk * 16));
      short8 va1 = *(const short8*)(VTc + SW(row, 64 + hk * 16));
      o1a[dt] = MFMA_B16(va0, p10, o1a[dt]);
      o1a[dt] = MFMA_B16(va1, p11, o1a[dt]);
      o2a[dt] = MFMA_B16(va0, p20, o2a[dt]);
      o2a[dt] = MFMA_B16(va1, p21, o2a[dt]);
    }
  }
#undef LOADT

  // softmax denominators: sum over 4 lane-groups (same q = lane&15)
  float l1 = l1p; l1 += __shfl_xor(l1, 16); l1 += __shfl_xor(l1, 32);
  float l2 = l2p; l2 += __shfl_xor(l2, 16); l2 += __shfl_xor(l2, 32);
  const float inv1 = 1.f / l1;
  const float inv2 = 1.f / l2;

  float av[8][4];
  float ss = 0.f;
#pragma unroll
  for (int dt = 0; dt < 8; dt++)
#pragma unroll
    for (int r = 0; r < 4; r++) {
      float a = o1a[dt][r] * inv1 - lam * (o2a[dt][r] * inv2);
      av[dt][r] = a;
      ss += a * a;
    }
  ss += __shfl_xor(ss, 16); ss += __shfl_xor(ss, 32);
  const float sc2 = rsqrtf(ss * (1.f / 128.f) + 1e-5f) * ONE_MINUS_LI;

  u16* orow = attnb + (size_t)(b * S_LEN + qrow) * EMB + h * 128;
#pragma unroll
  for (int dt = 0; dt < 8; dt++) {
    int d = dt * 16 + hk * 4;
    f32x4 gv = *(const f32x4*)&gamma[d];
    unsigned long long pk = (unsigned long long)f2bf(av[dt][0] * gv[0] * sc2)
                          | ((unsigned long long)f2bf(av[dt][1] * gv[1] * sc2) << 16)
                          | ((unsigned long long)f2bf(av[dt][2] * gv[2] * sc2) << 32)
                          | ((unsigned long long)f2bf(av[dt][3] * gv[3] * sc2) << 48);
    *(unsigned long long*)&orow[d] = pk;
  }
}

// ---------------- launcher ----------------
extern "C" void kernel_launch(void* const* d_in, const int* in_sizes, int n_in,
                              void* d_out, int out_size, void* d_ws, size_t ws_size,
                              hipStream_t stream) {
  (void)in_sizes; (void)n_in; (void)out_size; (void)ws_size;
  const float* x   = (const float*)d_in[0];
  const float* Wq  = (const float*)d_in[1];
  const float* Wk  = (const float*)d_in[2];
  const float* Wv  = (const float*)d_in[3];
  const float* Wo  = (const float*)d_in[4];
  const float* lq1 = (const float*)d_in[5];
  const float* lk1 = (const float*)d_in[6];
  const float* lq2 = (const float*)d_in[7];
  const float* lk2 = (const float*)d_in[8];
  const float* gam = (const float*)d_in[9];

  char* ws = (char*)d_ws;
  u16* xb    = (u16*)(ws);                          // 4096x2048 bf16
  u16* Wcat  = (u16*)(ws + 16777216);               // 6144x2048 bf16
  u16* Wob   = (u16*)(ws + 41943040);               // 2048x2048 bf16
  u16* qkv   = (u16*)(ws + 50331648);               // 4096x6144 bf16
  u16* attnb = xb;                                  // alias: x dead after QKV GEMM

  const int NE = EMB * EMB;
  cvt_f32_bf16<<<(2 * NE / 4 + 255) / 256, 256, 0, stream>>>(x, xb, 2 * NE / 4);
  cvt_f32_bf16<<<(NE / 4 + 255) / 256, 256, 0, stream>>>(Wq, Wcat, NE / 4);
  cvt_f32_bf16<<<(NE / 4 + 255) / 256, 256, 0, stream>>>(Wk, Wcat + NE, NE / 4);
  cvt_f32_bf16<<<(NE / 4 + 255) / 256, 256, 0, stream>>>(Wv, Wcat + 2 * NE, NE / 4);
  cvt_f32_bf16<<<(NE / 4 + 255) / 256, 256, 0, stream>>>(Wo, Wob, NE / 4);

  dim3 g1(4096 / 128, QKV_N / 128);
  gemm_bt<1><<<g1, 256, 0, stream>>>(xb, Wcat, qkv, 4096, QKV_N, EMB);

  rope_kernel<<<(4096 * 64 * 32) / 256, 256, 0, stream>>>(qkv);

  attn_kernel<<<1024, 256, 0, stream>>>(qkv, attnb, lq1, lk1, lq2, lk2, gam);

  dim3 g2(4096 / 128, EMB / 128);
  gemm_bt<0><<<g2, 256, 0, stream>>>(attnb, Wob, d_out, 4096, EMB, EMB);
}

// Round 4
// 360.898 us; speedup vs baseline: 1.5102x; 1.5102x over previous
//
#include <hip/hip_runtime.h>
#include <cstdint>
#include <cstddef>

typedef unsigned short u16;
typedef __attribute__((ext_vector_type(8))) short short8;
typedef __attribute__((ext_vector_type(4))) float f32x4;

#define MFMA_B16(a,b,c) __builtin_amdgcn_mfma_f32_16x16x32_bf16((a),(b),(c),0,0,0)

#define S_LEN 2048
#define EMB 2048
#define QKV_N 6144
#define HD 64
#define LAMBDA_INIT_F 0.78360576653162f
#define ONE_MINUS_LI 0.21639423346838f

static __device__ __forceinline__ u16 f2bf(float f) {
  unsigned u = __float_as_uint(f);
  unsigned r = ((u >> 16) & 1u) + 0x7fffu;
  return (u16)((u + r) >> 16);
}
static __device__ __forceinline__ float bf2f(u16 h) {
  return __uint_as_float(((unsigned)h) << 16);
}
static __device__ __forceinline__ unsigned cvt_pk_bf16(float lo, float hi) {
  unsigned r;
  asm("v_cvt_pk_bf16_f32 %0, %1, %2" : "=v"(r) : "v"(lo), "v"(hi));
  return r;
}
static __device__ __forceinline__ void gload_lds16(const u16* g, u16* l) {
  __builtin_amdgcn_global_load_lds((const __attribute__((address_space(1))) void*)g,
                                   (__attribute__((address_space(3))) void*)l, 16, 0, 0);
}

// ---------------- f32 -> bf16 convert (vectorized) ----------------
__global__ void cvt_f32_bf16(const float* __restrict__ s, u16* __restrict__ d, int n4) {
  int i = blockIdx.x * 256 + threadIdx.x;
  if (i >= n4) return;
  f32x4 v = *(const f32x4*)&s[i * 4];
  unsigned lo = cvt_pk_bf16(v[0], v[1]);
  unsigned hi = cvt_pk_bf16(v[2], v[3]);
  *(unsigned long long*)&d[i * 4] = (unsigned long long)lo | ((unsigned long long)hi << 32);
}

// ---------------- GEMM: C[M,N] = A[M,K] * B[N,K]^T  (bf16 in, f32 acc) ----------------
template <int BF16OUT>
__global__ __launch_bounds__(256, 2) void gemm_bt(const u16* __restrict__ A,
                                                  const u16* __restrict__ B,
                                                  void* __restrict__ Cout,
                                                  int M, int N, int K) {
  __shared__ u16 As[128 * 32];
  __shared__ u16 Bs[128 * 32];
  const int tid = threadIdx.x;
  const int lane = tid & 63, wv = tid >> 6;
  const int bm = blockIdx.x * 128, bn = blockIdx.y * 128;
  const int wr = (wv >> 1) * 64, wc = (wv & 1) * 64;
  const int lr = lane & 15, hk = lane >> 4;

  const int r0 = tid >> 2;
  const int c0 = (tid & 3) * 8;
  const u16* ga = A + (size_t)(bm + r0) * K + c0;
  const u16* gb = B + (size_t)(bn + r0) * K + c0;
  const size_t rstep = (size_t)64 * K;

  f32x4 acc[4][4] = {};

  for (int k0 = 0; k0 < K; k0 += 32) {
    __syncthreads();
    gload_lds16(ga + k0,         &As[(tid) * 8]);
    gload_lds16(ga + rstep + k0, &As[(tid + 256) * 8]);
    gload_lds16(gb + k0,         &Bs[(tid) * 8]);
    gload_lds16(gb + rstep + k0, &Bs[(tid + 256) * 8]);
    __syncthreads();
    short8 af[4], bfv[4];
#pragma unroll
    for (int i = 0; i < 4; i++) af[i] = *(const short8*)&As[(wr + i * 16 + lr) * 32 + hk * 8];
#pragma unroll
    for (int j = 0; j < 4; j++) bfv[j] = *(const short8*)&Bs[(wc + j * 16 + lr) * 32 + hk * 8];
#pragma unroll
    for (int i = 0; i < 4; i++)
#pragma unroll
      for (int j = 0; j < 4; j++)
        acc[i][j] = MFMA_B16(af[i], bfv[j], acc[i][j]);
  }

  if (BF16OUT) {
    u16* C = (u16*)Cout;
#pragma unroll
    for (int i = 0; i < 4; i++)
#pragma unroll
      for (int j = 0; j < 4; j++)
#pragma unroll
        for (int r = 0; r < 4; r++) {
          int row = bm + wr + i * 16 + hk * 4 + r;
          int col = bn + wc + j * 16 + lr;
          C[(size_t)row * N + col] = f2bf(acc[i][j][r]);
        }
  } else {
    float* C = (float*)Cout;
#pragma unroll
    for (int i = 0; i < 4; i++)
#pragma unroll
      for (int j = 0; j < 4; j++)
#pragma unroll
        for (int r = 0; r < 4; r++) {
          int row = bm + wr + i * 16 + hk * 4 + r;
          int col = bn + wc + j * 16 + lr;
          C[(size_t)row * N + col] = acc[i][j][r];
        }
  }
}

// ---------------- RoPE (interleaved, in place on q,k halves of qkv) ----------------
__global__ void rope_kernel(u16* __restrict__ qkv) {
  int idx = blockIdx.x * 256 + threadIdx.x;
  int p = idx & 31;
  int u = (idx >> 5) & 63;
  int m = idx >> 11;
  int t = m & (S_LEN - 1);
  int col = (u < 32) ? (u * 64 + 2 * p) : (EMB + (u - 32) * 64 + 2 * p);
  u16* ptr = qkv + (size_t)m * QKV_N + col;
  unsigned v = *(unsigned*)ptr;
  float xe = bf2f((u16)(v & 0xffff));
  float xo = bf2f((u16)(v >> 16));
  float w = expf((float)p * (-9.210340371976184f / 31.0f));
  float ang = (float)t * w;
  float sn, cs;
  sincosf(ang, &sn, &cs);
  float oe = xe * cs - xo * sn;
  float oo = xe * sn + xo * cs;
  *(unsigned*)ptr = (unsigned)f2bf(oe) | (((unsigned)f2bf(oo)) << 16);
}

// ---------------- fused dual-stream attention + lambda-combine + RMSNorm ----------------
// LDS: stride-64 rows (128 B) with XOR swizzle byte = row*128 + (colByte ^ ((row&7)<<4)).
#define SW(row, colByte) ((((row)) << 7) + ((colByte) ^ (((row) & 7) << 4)))

__global__ __launch_bounds__(256, 2) void attn_kernel(
    const u16* __restrict__ qkv, u16* __restrict__ attnb,
    const float* __restrict__ lq1, const float* __restrict__ lk1,
    const float* __restrict__ lq2, const float* __restrict__ lk2,
    const float* __restrict__ gamma) {
  __shared__ u16 K1s[64 * 64];
  __shared__ u16 K2s[64 * 64];
  __shared__ u16 VTs[128 * 64];
  __shared__ u16 Ps[4 * 2 * 16 * 64];  // per-wave P1,P2 sub-buffers (16 rows x 128 B)

  // XCD-clustered mapping: each XCD owns 4 (b,h) pairs -> K/V stays L2-resident
  const int g = blockIdx.x;
  const int xcd = g & 7;
  const int gi = g >> 3;
  const int bh = xcd * 4 + (gi >> 5);
  const int qt = gi & 31;
  const int b = bh >> 4, h = bh & 15;

  const int tid = threadIdx.x, lane = tid & 63, wv = tid >> 6;
  const int lr = lane & 15, hk = lane >> 4;

  // lambda via wave-parallel reduction (HD == 64 == wave width)
  float d1 = lq1[lane] * lk1[lane];
  float d2 = lq2[lane] * lk2[lane];
#pragma unroll
  for (int off = 32; off; off >>= 1) { d1 += __shfl_xor(d1, off); d2 += __shfl_xor(d2, off); }
  const float lam = __expf(d1) - __expf(d2) + LAMBDA_INIT_F;

  // Q fragments (B-operand of swapped QK^T)
  const int qrow = qt * 64 + wv * 16 + lr;
  const u16* qp = qkv + (size_t)(b * S_LEN + qrow) * QKV_N;
  short8 q1f[2], q2f[2];
  q1f[0] = *(const short8*)&qp[(2 * h) * 64 + hk * 8];
  q1f[1] = *(const short8*)&qp[(2 * h) * 64 + 32 + hk * 8];
  q2f[0] = *(const short8*)&qp[(2 * h + 1) * 64 + hk * 8];
  q2f[1] = *(const short8*)&qp[(2 * h + 1) * 64 + 32 + hk * 8];

  f32x4 o1a[8] = {};
  f32x4 o2a[8] = {};
  float l1p = 0.f, l2p = 0.f;

  // gload_lds K addressing: pre-swizzled global source, linear LDS dest.
  // lane L covers row (wv*8 + (L>>3)) (+32 for 2nd issue), 16B block (L&7)
  // linearly; source col-block = (L&7) ^ (L>>3) so LDS holds SW layout.
  const int gl_row = wv * 8 + (lane >> 3);
  const int gl_cb  = ((lane & 7) ^ (lane >> 3)) * 8;
  u16* k1d = &K1s[(wv * 8) * 64 + lane * 8];
  u16* k2d = &K2s[(wv * 8) * 64 + lane * 8];

  const int vkv = (tid & 31) * 2;     // V stage kv pair
  const int vd0 = (tid >> 5) * 8;     // V stage d block

  const u16* kb1 = qkv + (size_t)b * S_LEN * QKV_N + EMB + (2 * h) * 64;
  const u16* kb2 = kb1 + 64;
  const u16* vbp = qkv + (size_t)b * S_LEN * QKV_N + 2 * EMB + h * 128;

  char* P1 = (char*)&Ps[(wv * 2 + 0) * 16 * 64];
  char* P2 = (char*)&Ps[(wv * 2 + 1) * 16 * 64];
  char* VTc = (char*)VTs;

  for (int kv0 = 0; kv0 < S_LEN; kv0 += 64) {
    __syncthreads();  // all waves done reading previous tile's LDS
    // K1,K2 -> LDS via async DMA (pre-swizzled source)
    {
      const u16* g1 = kb1 + (size_t)(kv0 + gl_row) * QKV_N + gl_cb;
      const u16* g2 = kb2 + (size_t)(kv0 + gl_row) * QKV_N + gl_cb;
      gload_lds16(g1, k1d);
      gload_lds16(g1 + (size_t)32 * QKV_N, k1d + 32 * 64);
      gload_lds16(g2, k2d);
      gload_lds16(g2 + (size_t)32 * QKV_N, k2d + 32 * 64);
    }
    // V: reg load -> packed transpose write (short live ranges)
    {
      const u16* vs = vbp + (size_t)(kv0 + vkv) * QKV_N + vd0;
      short8 a0 = *(const short8*)vs;
      short8 a1 = *(const short8*)(vs + QKV_N);
      short8 b0 = *(const short8*)(vs + 64);
      short8 b1 = *(const short8*)(vs + QKV_N + 64);
#pragma unroll
      for (int j = 0; j < 8; j++) {
        unsigned pk0 = (unsigned)(u16)a0[j] | (((unsigned)(u16)a1[j]) << 16);
        *(unsigned*)(VTc + SW(vd0 + j, vkv * 2)) = pk0;
        unsigned pk1 = (unsigned)(u16)b0[j] | (((unsigned)(u16)b1[j]) << 16);
        *(unsigned*)(VTc + SW(vd0 + 64 + j, vkv * 2)) = pk1;
      }
    }
    __syncthreads();  // drains vmcnt/lgkm -> K,V tile ready

    // scores (swapped: S^T tile = mfma(K, Q)), exp, write P (bf16) to per-wave LDS
#pragma unroll
    for (int st = 0; st < 2; st++) {
      const char* Ks = st ? (char*)K2s : (char*)K1s;
      const short8* qf = st ? q2f : q1f;
      char* Pw = st ? P2 : P1;
      float lacc = 0.f;
#pragma unroll
      for (int kt = 0; kt < 4; kt++) {
        f32x4 s = {0.f, 0.f, 0.f, 0.f};
        int row = kt * 16 + lr;
        short8 ka0 = *(const short8*)(Ks + SW(row, hk * 16));
        short8 ka1 = *(const short8*)(Ks + SW(row, 64 + hk * 16));
        s = MFMA_B16(ka0, qf[0], s);
        s = MFMA_B16(ka1, qf[1], s);
        float e0 = __expf(s[0] * 0.125f);
        float e1 = __expf(s[1] * 0.125f);
        float e2 = __expf(s[2] * 0.125f);
        float e3 = __expf(s[3] * 0.125f);
        lacc += (e0 + e1) + (e2 + e3);
        unsigned plo = cvt_pk_bf16(e0, e1);
        unsigned phi = cvt_pk_bf16(e2, e3);
        *(unsigned long long*)(Pw + SW(lr, kt * 32 + hk * 8)) =
            (unsigned long long)plo | ((unsigned long long)phi << 32);
      }
      if (st) l2p += lacc; else l1p += lacc;
    }
    asm volatile("" ::: "memory");  // keep P LDS writes ordered before P reads

    // PV: o^T = mfma(V^T, P^T); V fragments shared by both streams
    short8 p10 = *(const short8*)(P1 + SW(lr, hk * 16));
    short8 p11 = *(const short8*)(P1 + SW(lr, 64 + hk * 16));
    short8 p20 = *(const short8*)(P2 + SW(lr, hk * 16));
    short8 p21 = *(const short8*)(P2 + SW(lr, 64 + hk * 16));
#pragma unroll
    for (int dt = 0; dt < 8; dt++) {
      int row = dt * 16 + lr;
      short8 va0 = *(const short8*)(VTc + SW(row, hk * 16));
      short8 va1 = *(const short8*)(VTc + SW(row, 64 + hk * 16));
      o1a[dt] = MFMA_B16(va0, p10, o1a[dt]);
      o1a[dt] = MFMA_B16(va1, p11, o1a[dt]);
      o2a[dt] = MFMA_B16(va0, p20, o2a[dt]);
      o2a[dt] = MFMA_B16(va1, p21, o2a[dt]);
    }
  }

  // softmax denominators: sum over 4 lane-groups (same q = lane&15)
  float l1 = l1p; l1 += __shfl_xor(l1, 16); l1 += __shfl_xor(l1, 32);
  float l2 = l2p; l2 += __shfl_xor(l2, 16); l2 += __shfl_xor(l2, 32);
  const float inv1 = 1.f / l1;
  const float inv2 = 1.f / l2;

  float av[8][4];
  float ss = 0.f;
#pragma unroll
  for (int dt = 0; dt < 8; dt++)
#pragma unroll
    for (int r = 0; r < 4; r++) {
      float a = o1a[dt][r] * inv1 - lam * (o2a[dt][r] * inv2);
      av[dt][r] = a;
      ss += a * a;
    }
  ss += __shfl_xor(ss, 16); ss += __shfl_xor(ss, 32);
  const float sc2 = rsqrtf(ss * (1.f / 128.f) + 1e-5f) * ONE_MINUS_LI;

  u16* orow = attnb + (size_t)(b * S_LEN + qrow) * EMB + h * 128;
#pragma unroll
  for (int dt = 0; dt < 8; dt++) {
    int d = dt * 16 + hk * 4;
    f32x4 gv = *(const f32x4*)&gamma[d];
    unsigned plo = cvt_pk_bf16(av[dt][0] * gv[0] * sc2, av[dt][1] * gv[1] * sc2);
    unsigned phi = cvt_pk_bf16(av[dt][2] * gv[2] * sc2, av[dt][3] * gv[3] * sc2);
    *(unsigned long long*)&orow[d] = (unsigned long long)plo | ((unsigned long long)phi << 32);
  }
}

// ---------------- launcher ----------------
extern "C" void kernel_launch(void* const* d_in, const int* in_sizes, int n_in,
                              void* d_out, int out_size, void* d_ws, size_t ws_size,
                              hipStream_t stream) {
  (void)in_sizes; (void)n_in; (void)out_size; (void)ws_size;
  const float* x   = (const float*)d_in[0];
  const float* Wq  = (const float*)d_in[1];
  const float* Wk  = (const float*)d_in[2];
  const float* Wv  = (const float*)d_in[3];
  const float* Wo  = (const float*)d_in[4];
  const float* lq1 = (const float*)d_in[5];
  const float* lk1 = (const float*)d_in[6];
  const float* lq2 = (const float*)d_in[7];
  const float* lk2 = (const float*)d_in[8];
  const float* gam = (const float*)d_in[9];

  char* ws = (char*)d_ws;
  u16* xb    = (u16*)(ws);                          // 4096x2048 bf16
  u16* Wcat  = (u16*)(ws + 16777216);               // 6144x2048 bf16
  u16* Wob   = (u16*)(ws + 41943040);               // 2048x2048 bf16
  u16* qkv   = (u16*)(ws + 50331648);               // 4096x6144 bf16
  u16* attnb = xb;                                  // alias: x dead after QKV GEMM

  const int NE = EMB * EMB;
  cvt_f32_bf16<<<(2 * NE / 4 + 255) / 256, 256, 0, stream>>>(x, xb, 2 * NE / 4);
  cvt_f32_bf16<<<(NE / 4 + 255) / 256, 256, 0, stream>>>(Wq, Wcat, NE / 4);
  cvt_f32_bf16<<<(NE / 4 + 255) / 256, 256, 0, stream>>>(Wk, Wcat + NE, NE / 4);
  cvt_f32_bf16<<<(NE / 4 + 255) / 256, 256, 0, stream>>>(Wv, Wcat + 2 * NE, NE / 4);
  cvt_f32_bf16<<<(NE / 4 + 255) / 256, 256, 0, stream>>>(Wo, Wob, NE / 4);

  dim3 g1(4096 / 128, QKV_N / 128);
  gemm_bt<1><<<g1, 256, 0, stream>>>(xb, Wcat, qkv, 4096, QKV_N, EMB);

  rope_kernel<<<(4096 * 64 * 32) / 256, 256, 0, stream>>>(qkv);

  attn_kernel<<<1024, 256, 0, stream>>>(qkv, attnb, lq1, lk1, lq2, lk2, gam);

  dim3 g2(4096 / 128, EMB / 128);
  gemm_bt<0><<<g2, 256, 0, stream>>>(attnb, Wob, d_out, 4096, EMB, EMB);
}